// Round 2
// baseline (314.036 us; speedup 1.0000x reference)
//
#include <hip/hip_runtime.h>
#include <stdint.h>

typedef unsigned short u16;
typedef short s16x8 __attribute__((ext_vector_type(8)));
typedef unsigned short u16x8 __attribute__((ext_vector_type(8)));
typedef float f32x4 __attribute__((ext_vector_type(4)));

#define GLD16(g, l) __builtin_amdgcn_global_load_lds( \
    (const __attribute__((address_space(1))) uint32_t*)(g), \
    (__attribute__((address_space(3))) uint32_t*)(l), 16, 0, 0)

__device__ __forceinline__ u16 f2bf(float f) {
  uint32_t u = __builtin_bit_cast(uint32_t, f);
  u += 0x7fffu + ((u >> 16) & 1u);
  return (u16)(u >> 16);
}

// ---------------- cast x (f32 -> bf16), 8 elems/thread ----------------
__global__ void cvt_kernel(const float* __restrict__ in, u16* __restrict__ out) {
  int i = blockIdx.x * 256 + threadIdx.x;
  const float4* p = (const float4*)in + (size_t)i * 2;
  float4 a = p[0], b = p[1];
  u16x8 o;
  o[0] = f2bf(a.x); o[1] = f2bf(a.y); o[2] = f2bf(a.z); o[3] = f2bf(a.w);
  o[4] = f2bf(b.x); o[5] = f2bf(b.y); o[6] = f2bf(b.z); o[7] = f2bf(b.w);
  *((u16x8*)out + i) = o;
}

// ------------- transpose f32 [bz][R][C] -> bf16 [bz][C][R] -------------
__global__ void transpose_f2b(const float* __restrict__ in, u16* __restrict__ out,
                              int R, int C) {
  __shared__ float tile[32][33];
  const int bz = blockIdx.z;
  in  += (size_t)bz * R * C;
  out += (size_t)bz * R * C;
  int c0 = blockIdx.x * 32, r0 = blockIdx.y * 32;
  int tx = threadIdx.x, ty = threadIdx.y;
  #pragma unroll
  for (int i = 0; i < 32; i += 8)
    tile[ty + i][tx] = in[(size_t)(r0 + ty + i) * C + c0 + tx];
  __syncthreads();
  #pragma unroll
  for (int i = 0; i < 32; i += 8)
    out[(size_t)(c0 + ty + i) * R + r0 + tx] = f2bf(tile[tx][ty + i]);
}

// ------------- transpose bf16 [bz][R][C] -> bf16 [bz][C][R] ------------
__global__ void transpose_b2b(const u16* __restrict__ in, u16* __restrict__ out,
                              int R, int C) {
  __shared__ u16 tile[32][33];
  const int bz = blockIdx.z;
  in  += (size_t)bz * R * C;
  out += (size_t)bz * R * C;
  int c0 = blockIdx.x * 32, r0 = blockIdx.y * 32;
  int tx = threadIdx.x, ty = threadIdx.y;
  #pragma unroll
  for (int i = 0; i < 32; i += 8)
    tile[ty + i][tx] = in[(size_t)(r0 + ty + i) * C + c0 + tx];
  __syncthreads();
  #pragma unroll
  for (int i = 0; i < 32; i += 8)
    out[(size_t)(c0 + ty + i) * R + r0 + tx] = tile[tx][ty + i];
}

// ---------------- 128x128x64 bf16 MFMA GEMM (m97 structure) ----------------
// A [M][K] bf16 row-major, Bt [N][K] bf16 (B transposed). EPI 0: qkv epilogue,
// EPI 1: f32 out + bias.
template <int EPI>
__global__ __launch_bounds__(256) void gemm128(
    const u16* __restrict__ A, const u16* __restrict__ Bt, int K,
    const float* __restrict__ bias,
    u16* __restrict__ kb, u16* __restrict__ qb, u16* __restrict__ vb,
    float* __restrict__ fout) {
  __shared__ __align__(16) u16 As[128 * 64];
  __shared__ __align__(16) u16 Bs[128 * 64];
  const int tid = threadIdx.x;
  const int lane = tid & 63;
  const int wr = (tid >> 6) >> 1, wc = (tid >> 6) & 1;
  const int row0 = blockIdx.y * 128, col0 = blockIdx.x * 128;
  const int l15 = lane & 15, l4 = lane >> 4;
  const u16* Ablk = A + (size_t)row0 * K;
  const u16* Bblk = Bt + (size_t)col0 * K;
  f32x4 acc[4][4] = {};
  for (int k0 = 0; k0 < K; k0 += 64) {
    #pragma unroll
    for (int i = 0; i < 4; i++) {
      int off = (i * 256 + tid) * 8;
      int r = off >> 6, c = off & 63;
      GLD16(Ablk + (size_t)r * K + k0 + c, As + off);
    }
    #pragma unroll
    for (int i = 0; i < 4; i++) {
      int off = (i * 256 + tid) * 8;
      int r = off >> 6, c = off & 63;
      GLD16(Bblk + (size_t)r * K + k0 + c, Bs + off);
    }
    __syncthreads();
    #pragma unroll
    for (int kc = 0; kc < 2; kc++) {
      s16x8 af[4], bfr[4];
      #pragma unroll
      for (int m = 0; m < 4; m++)
        af[m] = *(const s16x8*)(As + (wr * 64 + m * 16 + l15) * 64 + kc * 32 + l4 * 8);
      #pragma unroll
      for (int n = 0; n < 4; n++)
        bfr[n] = *(const s16x8*)(Bs + (wc * 64 + n * 16 + l15) * 64 + kc * 32 + l4 * 8);
      #pragma unroll
      for (int m = 0; m < 4; m++)
        #pragma unroll
        for (int n = 0; n < 4; n++)
          acc[m][n] = __builtin_amdgcn_mfma_f32_16x16x32_bf16(af[m], bfr[n], acc[m][n], 0, 0, 0);
    }
    __syncthreads();
  }
  const int rbase = row0 + wr * 64;
  const int cbase = col0 + wc * 64;
  if (EPI == 0) {
    // columns map: h = c/192; c%192 in [0,64)->k, [64,128)->q, [128,192)->v
    #pragma unroll
    for (int n = 0; n < 4; n++) {
      int c = cbase + n * 16 + l15;
      int h = c / 192, rr = c % 192;
      int part = rr >> 6, d = rr & 63;
      float bv = bias[h * 192 + rr];
      u16* dst = (part == 0) ? kb : (part == 1) ? qb : vb;
      float sc = (part == 1) ? 0.125f : 1.0f;  // fold 1/sqrt(hd) into q
      #pragma unroll
      for (int m = 0; m < 4; m++)
        #pragma unroll
        for (int i = 0; i < 4; i++) {
          int r = rbase + m * 16 + l4 * 4 + i;
          int b = r >> 11, nn = r & 2047;
          dst[(((size_t)(b * 16 + h) * 2048 + nn) << 6) + d] = f2bf((acc[m][n][i] + bv) * sc);
        }
    }
  } else {
    #pragma unroll
    for (int n = 0; n < 4; n++) {
      int c = cbase + n * 16 + l15;
      float bv = bias[c];
      #pragma unroll
      for (int m = 0; m < 4; m++)
        #pragma unroll
        for (int i = 0; i < 4; i++) {
          int r = rbase + m * 16 + l4 * 4 + i;
          fout[(size_t)r * 1024 + c] = acc[m][n][i] + bv;
        }
    }
  }
}

// ---------------- causal flash attention ----------------
// q,k: [BH=32][2048][64] bf16 (q pre-scaled by 0.125); vt: [32][64][2048] bf16
// sa out: [B=2][2048][1024] bf16 (concat heads)
__global__ __launch_bounds__(256) void attn_kernel(
    const u16* __restrict__ q, const u16* __restrict__ k,
    const u16* __restrict__ vt, u16* __restrict__ sa) {
  __shared__ __align__(16) u16 Ks[64 * 64];   // [kv][d]
  __shared__ __align__(16) u16 Vs[64 * 64];   // VT tile [hd][kv]
  __shared__ __align__(16) u16 Ps[4][16][72]; // per-wave P, padded rows
  const int tid = threadIdx.x;
  const int lane = tid & 63;
  const int wave = tid >> 6;
  const int l15 = lane & 15, l4 = lane >> 4;
  const int bh = blockIdx.y;
  const int qt = 31 - blockIdx.x;  // big blocks first

  // Q fragments: row = l15 (wave-local), k = kc*32 + 8*l4 + j
  const u16* qrow = q + (((size_t)bh * 2048 + qt * 64 + wave * 16 + l15) << 6);
  s16x8 qf0 = *(const s16x8*)(qrow + l4 * 8);
  s16x8 qf1 = *(const s16x8*)(qrow + 32 + l4 * 8);

  f32x4 o[4] = {};
  float mrow[4], lrow[4];
  #pragma unroll
  for (int r = 0; r < 4; r++) { mrow[r] = -3e38f; lrow[r] = 0.f; }

  for (int kt = 0; kt <= qt; kt++) {
    // stage K tile [64][64] and VT tile [64 hd][64 kv]
    #pragma unroll
    for (int i = 0; i < 2; i++) {
      int off = (i * 256 + tid) * 8;
      int r = off >> 6, c = off & 63;
      GLD16(k + (((size_t)bh * 2048 + kt * 64 + r) << 6) + c, Ks + off);
      GLD16(vt + ((size_t)bh * 64 + r) * 2048 + kt * 64 + c, Vs + off);
    }
    __syncthreads();

    // S = Q K^T : 4 col tiles x 2 k-chunks
    f32x4 s[4] = {};
    #pragma unroll
    for (int t = 0; t < 4; t++) {
      s16x8 kf0 = *(const s16x8*)(Ks + (t * 16 + l15) * 64 + l4 * 8);
      s16x8 kf1 = *(const s16x8*)(Ks + (t * 16 + l15) * 64 + 32 + l4 * 8);
      s[t] = __builtin_amdgcn_mfma_f32_16x16x32_bf16(qf0, kf0, s[t], 0, 0, 0);
      s[t] = __builtin_amdgcn_mfma_f32_16x16x32_bf16(qf1, kf1, s[t], 0, 0, 0);
    }
    // causal mask on diagonal tile
    if (kt == qt) {
      #pragma unroll
      for (int t = 0; t < 4; t++)
        #pragma unroll
        for (int i = 0; i < 4; i++)
          if (t * 16 + l15 > wave * 16 + l4 * 4 + i) s[t][i] = -3e38f;
    }
    // online softmax per row r (rows live in 16-lane groups)
    float p[4][4];
    #pragma unroll
    for (int r = 0; r < 4; r++) {
      float sm = fmaxf(fmaxf(s[0][r], s[1][r]), fmaxf(s[2][r], s[3][r]));
      #pragma unroll
      for (int off = 1; off < 16; off <<= 1)
        sm = fmaxf(sm, __shfl_xor(sm, off));
      float mn = fmaxf(mrow[r], sm);
      float alpha = __expf(mrow[r] - mn);
      mrow[r] = mn;
      float rs = 0.f;
      #pragma unroll
      for (int t = 0; t < 4; t++) {
        float pv = __expf(s[t][r] - mn);
        p[t][r] = pv;
        rs += pv;
      }
      #pragma unroll
      for (int off = 1; off < 16; off <<= 1)
        rs += __shfl_xor(rs, off);
      lrow[r] = lrow[r] * alpha + rs;
      #pragma unroll
      for (int t = 0; t < 4; t++) o[t][r] *= alpha;
    }
    // P (D-layout) -> LDS -> A-frag layout
    #pragma unroll
    for (int t = 0; t < 4; t++)
      #pragma unroll
      for (int r = 0; r < 4; r++)
        Ps[wave][l4 * 4 + r][t * 16 + l15] = f2bf(p[t][r]);
    s16x8 pa0 = *(const s16x8*)&Ps[wave][l15][l4 * 8];
    s16x8 pa1 = *(const s16x8*)&Ps[wave][l15][32 + l4 * 8];
    // O += P V : B-frag from VT tile, col(hd) = t*16+l15, k(kv) = kc*32+8*l4+j
    #pragma unroll
    for (int t = 0; t < 4; t++) {
      s16x8 vf0 = *(const s16x8*)(Vs + (t * 16 + l15) * 64 + l4 * 8);
      s16x8 vf1 = *(const s16x8*)(Vs + (t * 16 + l15) * 64 + 32 + l4 * 8);
      o[t] = __builtin_amdgcn_mfma_f32_16x16x32_bf16(pa0, vf0, o[t], 0, 0, 0);
      o[t] = __builtin_amdgcn_mfma_f32_16x16x32_bf16(pa1, vf1, o[t], 0, 0, 0);
    }
    __syncthreads();
  }
  // epilogue: normalize, write sa[b][n][h*64 + d] bf16
  const int b = bh >> 4, h = bh & 15;
  #pragma unroll
  for (int r = 0; r < 4; r++) {
    float inv = 1.f / lrow[r];
    int n = qt * 64 + wave * 16 + l4 * 4 + r;
    u16* dst = sa + ((size_t)(b * 2048 + n) << 10) + h * 64;
    #pragma unroll
    for (int t = 0; t < 4; t++)
      dst[t * 16 + l15] = f2bf(o[t][r] * inv);
  }
}

extern "C" void kernel_launch(void* const* d_in, const int* in_sizes, int n_in,
                              void* d_out, int out_size, void* d_ws, size_t ws_size,
                              hipStream_t stream) {
  const float* x    = (const float*)d_in[0];
  const float* Wqkv = (const float*)d_in[1];
  const float* bqkv = (const float*)d_in[2];
  const float* Wo   = (const float*)d_in[3];
  const float* bo   = (const float*)d_in[4];
  float* out = (float*)d_out;

  // workspace carve (u16 elements)
  u16* xb  = (u16*)d_ws;          // [4096][1024] (reused as sab after qkv gemm)
  u16* wqt = xb + 4194304;        // [16*192][1024]  (B^T for qkv gemm)
  u16* wot = wqt + 3145728;       // [1024][1024]    (B^T for out gemm)
  u16* qb  = wot + 1048576;       // [32][2048][64]
  u16* kb  = qb + 4194304;
  u16* vb  = kb + 4194304;
  u16* vtb = vb + 4194304;        // [32][64][2048]
  u16* sab = xb;                  // alias: x's bf16 copy is dead after qkv gemm

  cvt_kernel<<<2048, 256, 0, stream>>>(x, xb);
  transpose_f2b<<<dim3(6, 32, 16), dim3(32, 8), 0, stream>>>(Wqkv, wqt, 1024, 192);
  transpose_f2b<<<dim3(32, 32, 1), dim3(32, 8), 0, stream>>>(Wo, wot, 1024, 1024);
  gemm128<0><<<dim3(24, 32), 256, 0, stream>>>(xb, wqt, 1024, bqkv, kb, qb, vb, nullptr);
  transpose_b2b<<<dim3(2, 64, 32), dim3(32, 8), 0, stream>>>(vb, vtb, 2048, 64);
  attn_kernel<<<dim3(32, 32), 256, 0, stream>>>(qb, kb, vtb, sab);
  gemm128<1><<<dim3(8, 32), 256, 0, stream>>>(sab, wot, 1024, bo, nullptr, nullptr, nullptr, out);
}